// Round 1
// baseline (46.925 us; speedup 1.0000x reference)
//
#include <hip/hip_runtime.h>
#include <math.h>

// Problem constants (from reference): B=8, N=4096, K=26, D=64, all float32.
#define BB 8
#define NN 4096
#define KK 26
#define DD 64
#define CH 64            // N-chunks per batch -> grid = BB*CH = 512 blocks
#define NPB (NN / CH)    // 64 n-rows per block

// out[b,k,d] = sigmoid( sum_n (t[b,n,d]*kn[d]+bn[d]) * (nb[b,n,k,d]*kt[d]+bt[d]) * a[b,n,k] )
__global__ __launch_bounds__(256) void gat_partial(
    const float* __restrict__ targets,    // (B,N,D)
    const float* __restrict__ neighbors,  // (B,N,K,D)
    const float* __restrict__ a,          // (B,N,K)
    const float* __restrict__ kt,         // (D) kernel_target
    const float* __restrict__ bt,         // (D) bias_target
    const float* __restrict__ kn,         // (D) kernel_neighbor
    const float* __restrict__ bn,         // (D) bias_neighbor
    float* __restrict__ out)              // (B,K,D) accumulated (pre-zeroed)
{
    const int b     = blockIdx.x / CH;
    const int chunk = blockIdx.x % CH;
    const int tid   = threadIdx.x;
    const int wave  = tid >> 6;
    const int lane  = tid & 63;
    const int d     = lane;

    const float kt_d = kt[d];
    const float bt_d = bt[d];
    const float kn_d = kn[d];
    const float bn_d = bn[d];

    float acc[KK];
#pragma unroll
    for (int k = 0; k < KK; ++k) acc[k] = 0.f;

    const int n0 = chunk * NPB;
    for (int n = n0 + wave; n < n0 + NPB; n += 4) {
        const size_t row = (size_t)(b * NN + n);
        const float tt = fmaf(targets[row * DD + d], kn_d, bn_d);
        const float* __restrict__ nbrow = neighbors + row * (size_t)(KK * DD);
        const float* __restrict__ arow  = a + row * KK;
#pragma unroll
        for (int k = 0; k < KK; ++k) {
            const float av = arow[k];                 // wave-uniform address -> broadcast
            const float nb = nbrow[k * DD + d];       // 256B coalesced per wave
            acc[k] = fmaf(tt * av, fmaf(nb, kt_d, bt_d), acc[k]);
        }
    }

    // Cross-wave reduction in LDS, then one atomicAdd per (k,d) per block.
    __shared__ float lds[4][KK * DD];
#pragma unroll
    for (int k = 0; k < KK; ++k) lds[wave][k * DD + lane] = acc[k];
    __syncthreads();

    for (int idx = tid; idx < KK * DD; idx += 256) {
        const float s = lds[0][idx] + lds[1][idx] + lds[2][idx] + lds[3][idx];
        atomicAdd(&out[b * (KK * DD) + idx], s);
    }
}

__global__ __launch_bounds__(256) void gat_sigmoid(float* __restrict__ out, int nelem) {
    const int i = blockIdx.x * blockDim.x + threadIdx.x;
    if (i < nelem) {
        const float x = out[i];
        out[i] = 1.f / (1.f + expf(-x));
    }
}

extern "C" void kernel_launch(void* const* d_in, const int* in_sizes, int n_in,
                              void* d_out, int out_size, void* d_ws, size_t ws_size,
                              hipStream_t stream) {
    const float* targets = (const float*)d_in[0];
    const float* neighbors = (const float*)d_in[1];
    const float* a = (const float*)d_in[2];
    const float* kt = (const float*)d_in[3];
    const float* bt = (const float*)d_in[4];
    const float* kn = (const float*)d_in[5];
    const float* bn = (const float*)d_in[6];
    float* out = (float*)d_out;

    // Accumulator must start at zero every call (harness poisons d_out once).
    hipMemsetAsync(d_out, 0, (size_t)out_size * sizeof(float), stream);

    gat_partial<<<BB * CH, 256, 0, stream>>>(targets, neighbors, a, kt, bt, kn, bn, out);
    gat_sigmoid<<<(out_size + 255) / 256, 256, 0, stream>>>(out, out_size);
}